// Round 1
// baseline (806.625 us; speedup 1.0000x reference)
//
#include <hip/hip_runtime.h>
#include <hip/hip_bf16.h>
#include <float.h>
#include <math.h>

#define N_NODES 1024
#define N_EDGES 524288
#define IN_C    64
#define HID_C   128
#define OUT_C   512
#define MLP_H   64
#define ADJ_WORDS 32   // 1024 bits per dst row

// ---------------------------------------------------------------------------
// adjacency bitmap build (dedup: max-agg is idempotent, duplicates collapse)
// ---------------------------------------------------------------------------
__global__ void k_zero_adj(unsigned int* __restrict__ adj) {
    int i = blockIdx.x * blockDim.x + threadIdx.x;
    if (i < N_NODES * ADJ_WORDS) adj[i] = 0u;
}

__global__ void k_build_adj(const int* __restrict__ ei, unsigned int* __restrict__ adj) {
    int e = blockIdx.x * blockDim.x + threadIdx.x;
    if (e >= N_EDGES) return;
    int src = ei[e];            // edge_index[0] = src
    int dst = ei[N_EDGES + e];  // edge_index[1] = dst
    atomicOr(&adj[dst * ADJ_WORDS + (src >> 5)], 1u << (src & 31));
}

// ---------------------------------------------------------------------------
// node transform 1: A1[n] = x[n] @ W1[0:64,:] + b1 ; B1[n] = x[n] @ W1[64:128,:]
// (first MLP layer is linear in concat -> split into per-node halves)
// ---------------------------------------------------------------------------
__global__ void k_xform1(const float* __restrict__ x, const float* __restrict__ W1,
                         const float* __restrict__ b1,
                         float* __restrict__ A1, float* __restrict__ B1) {
    int n = blockIdx.x, t = threadIdx.x;  // 64 threads
    __shared__ float xs[IN_C];
    xs[t] = x[n * IN_C + t];
    __syncthreads();
    float a = b1[t], b = 0.f;
#pragma unroll
    for (int k = 0; k < IN_C; ++k) {
        float xv = xs[k];
        a = fmaf(xv, W1[k * MLP_H + t], a);
        b = fmaf(xv, W1[(IN_C + k) * MLP_H + t], b);
    }
    A1[n * MLP_H + t] = a;
    B1[n * MLP_H + t] = b;
}

// node transform 2: A2[n] = h1[n] @ W3[0:128,:] + b3 ; B2[n] = h1[n] @ W3[128:256,:]
__global__ void k_xform2(const float* __restrict__ h1, const float* __restrict__ W3,
                         const float* __restrict__ b3,
                         float* __restrict__ A2, float* __restrict__ B2) {
    int n = blockIdx.x, t = threadIdx.x;  // 64 threads
    __shared__ float hs[HID_C];
    hs[t] = h1[n * HID_C + t];
    hs[t + 64] = h1[n * HID_C + t + 64];
    __syncthreads();
    float a = b3[t], b = 0.f;
#pragma unroll
    for (int k = 0; k < HID_C; ++k) {
        float hv = hs[k];
        a = fmaf(hv, W3[k * MLP_H + t], a);
        b = fmaf(hv, W3[(HID_C + k) * MLP_H + t], b);
    }
    A2[n * MLP_H + t] = a;
    B2[n * MLP_H + t] = b;
}

// ---------------------------------------------------------------------------
// fused edge-MLP second layer + segment-max. One block per dst node.
// Thread owns CPT output channels; W-columns live in registers (static idx).
// z vectors (relu(A[dst]+B[src])) staged in double-buffered LDS, 32 at a time.
// ---------------------------------------------------------------------------
template <int NT, int CPT, int C_TOTAL>
__global__ __launch_bounds__(NT) void k_conv(
        const unsigned int* __restrict__ adj,
        const float* __restrict__ Anode, const float* __restrict__ Bnode,
        const float* __restrict__ W, const float* __restrict__ bias_g,
        float* __restrict__ out) {
    constexpr int BATCH = 32;
    constexpr int Q = MLP_H / 4;  // 16 float4 per z vector
    __shared__ unsigned short list[N_NODES];
    __shared__ float4 zbuf[2][BATCH][Q];
    __shared__ float4 as4[Q];
    __shared__ int cnt;

    const int i = blockIdx.x, tid = threadIdx.x;
    if (tid == 0) cnt = 0;
    if (tid < MLP_H) ((float*)as4)[tid] = Anode[i * MLP_H + tid];
    __syncthreads();

    // compact set bits of adjacency row into LDS list (order irrelevant for max)
    for (int w = tid; w < ADJ_WORDS; w += NT) {
        unsigned int bits = adj[i * ADJ_WORDS + w];
        while (bits) {
            int b = __ffs(bits) - 1;
            bits &= bits - 1;
            int pos = atomicAdd(&cnt, 1);
            list[pos] = (unsigned short)(w * 32 + b);
        }
    }
    __syncthreads();
    const int deg = cnt;

    // per-thread weight columns in registers (fully unrolled -> static indices)
    float wcol[CPT][MLP_H];
#pragma unroll
    for (int c = 0; c < CPT; ++c)
#pragma unroll
        for (int k = 0; k < MLP_H; ++k)
            wcol[c][k] = W[k * C_TOTAL + c * NT + tid];

    float bv[CPT], acc[CPT];
#pragma unroll
    for (int c = 0; c < CPT; ++c) {
        bv[c] = bias_g[c * NT + tid];
        acc[c] = -INFINITY;
    }

    auto fill = [&](int buf, int base, int nb) {
        for (int s = tid; s < nb * Q; s += NT) {
            int e = s >> 4;
            int q = s & (Q - 1);
            int j = list[base + e];
            float4 bb = ((const float4*)Bnode)[j * Q + q];
            float4 aa = as4[q];
            float4 z;
            z.x = fmaxf(aa.x + bb.x, 0.f);
            z.y = fmaxf(aa.y + bb.y, 0.f);
            z.z = fmaxf(aa.z + bb.z, 0.f);
            z.w = fmaxf(aa.w + bb.w, 0.f);
            zbuf[buf][e][q] = z;
        }
    };

    if (deg > 0) fill(0, 0, min(BATCH, deg));
    __syncthreads();

    int cur = 0;
    for (int b0 = 0; b0 < deg; b0 += BATCH) {
        int nb = min(BATCH, deg - b0);
        int nxt = b0 + BATCH;
        if (nxt < deg) fill(cur ^ 1, nxt, min(BATCH, deg - nxt));
        for (int e = 0; e < nb; ++e) {
            const float4* zp = zbuf[cur][e];
            float m0[CPT], m1[CPT];
#pragma unroll
            for (int c = 0; c < CPT; ++c) { m0[c] = bv[c]; m1[c] = 0.f; }
#pragma unroll
            for (int q = 0; q < Q; q += 2) {
                float4 z4 = zp[q];
                float4 z5 = zp[q + 1];
#pragma unroll
                for (int c = 0; c < CPT; ++c) {
                    m0[c] = fmaf(z4.x, wcol[c][4 * q + 0], m0[c]);
                    m0[c] = fmaf(z4.y, wcol[c][4 * q + 1], m0[c]);
                    m0[c] = fmaf(z4.z, wcol[c][4 * q + 2], m0[c]);
                    m0[c] = fmaf(z4.w, wcol[c][4 * q + 3], m0[c]);
                    m1[c] = fmaf(z5.x, wcol[c][4 * q + 4], m1[c]);
                    m1[c] = fmaf(z5.y, wcol[c][4 * q + 5], m1[c]);
                    m1[c] = fmaf(z5.z, wcol[c][4 * q + 6], m1[c]);
                    m1[c] = fmaf(z5.w, wcol[c][4 * q + 7], m1[c]);
                }
            }
#pragma unroll
            for (int c = 0; c < CPT; ++c) acc[c] = fmaxf(acc[c], m0[c] + m1[c]);
        }
        __syncthreads();
        cur ^= 1;
    }

#pragma unroll
    for (int c = 0; c < CPT; ++c)
        out[i * C_TOTAL + c * NT + tid] = (deg == 0) ? 0.f : acc[c];
}

// ---------------------------------------------------------------------------
// readout: out[c][o] = sum_n h2[n][c] * Wr[n][o] + br[o]   (512x1024 @ 1024x512)
// ---------------------------------------------------------------------------
__global__ __launch_bounds__(256) void k_readout(
        const float* __restrict__ h2, const float* __restrict__ Wr,
        const float* __restrict__ br, float* __restrict__ out) {
    __shared__ float At[64][65];  // At[c][k] (transposed h2 tile)
    __shared__ float Bt[64][65];  // Bt[k][o]
    const int c0 = (blockIdx.x / 8) * 64;
    const int o0 = (blockIdx.x % 8) * 64;
    const int tid = threadIdx.x;
    const int tx = tid % 16, ty = tid / 16;
    float acc[4][4] = {};
    for (int k0 = 0; k0 < N_NODES; k0 += 64) {
        for (int s = tid; s < 64 * 64; s += 256) {
            int r = s / 64, cc = s % 64;
            At[cc][r] = h2[(k0 + r) * OUT_C + c0 + cc];
            Bt[r][cc] = Wr[(k0 + r) * OUT_C + o0 + cc];
        }
        __syncthreads();
#pragma unroll 8
        for (int kk = 0; kk < 64; ++kk) {
            float a[4], b[4];
#pragma unroll
            for (int u = 0; u < 4; ++u) a[u] = At[ty * 4 + u][kk];
#pragma unroll
            for (int v = 0; v < 4; ++v) b[v] = Bt[kk][tx * 4 + v];
#pragma unroll
            for (int u = 0; u < 4; ++u)
#pragma unroll
                for (int v = 0; v < 4; ++v) acc[u][v] = fmaf(a[u], b[v], acc[u][v]);
        }
        __syncthreads();
    }
#pragma unroll
    for (int u = 0; u < 4; ++u)
#pragma unroll
        for (int v = 0; v < 4; ++v)
            out[(c0 + ty * 4 + u) * OUT_C + (o0 + tx * 4 + v)] = acc[u][v] + br[o0 + tx * 4 + v];
}

// ---------------------------------------------------------------------------
extern "C" void kernel_launch(void* const* d_in, const int* in_sizes, int n_in,
                              void* d_out, int out_size, void* d_ws, size_t ws_size,
                              hipStream_t stream) {
    const float* x  = (const float*)d_in[0];
    const int*   ei = (const int*)d_in[1];
    const float* W1 = (const float*)d_in[2];
    const float* b1 = (const float*)d_in[3];
    const float* W2 = (const float*)d_in[4];
    const float* b2 = (const float*)d_in[5];
    const float* W3 = (const float*)d_in[6];
    const float* b3 = (const float*)d_in[7];
    const float* W4 = (const float*)d_in[8];
    const float* b4 = (const float*)d_in[9];
    const float* Wr = (const float*)d_in[10];
    const float* br = (const float*)d_in[11];
    float* out = (float*)d_out;

    // workspace partition (all 256B-aligned)
    char* ws = (char*)d_ws;
    unsigned int* adj = (unsigned int*)ws;                 // 131072 B
    float* A1 = (float*)(ws + 131072);                     // 262144 B
    float* B1 = (float*)(ws + 393216);                     // 262144 B
    float* h1 = (float*)(ws + 655360);                     // 524288 B
    float* A2 = (float*)(ws + 1179648);                    // 262144 B
    float* B2 = (float*)(ws + 1441792);                    // 262144 B
    float* h2 = (float*)(ws + 1703936);                    // 2097152 B
    // total 3801088 B

    k_zero_adj<<<dim3((N_NODES * ADJ_WORDS + 255) / 256), dim3(256), 0, stream>>>(adj);
    k_build_adj<<<dim3(N_EDGES / 256), dim3(256), 0, stream>>>(ei, adj);
    k_xform1<<<dim3(N_NODES), dim3(64), 0, stream>>>(x, W1, b1, A1, B1);
    k_conv<128, 1, HID_C><<<dim3(N_NODES), dim3(128), 0, stream>>>(adj, A1, B1, W2, b2, h1);
    k_xform2<<<dim3(N_NODES), dim3(64), 0, stream>>>(h1, W3, b3, A2, B2);
    k_conv<256, 2, OUT_C><<<dim3(N_NODES), dim3(256), 0, stream>>>(adj, A2, B2, W4, b4, h2);
    k_readout<<<dim3(64), dim3(256), 0, stream>>>(h2, Wr, br, out);
}

// Round 2
// 287.304 us; speedup vs baseline: 2.8076x; 2.8076x over previous
//
#include <hip/hip_runtime.h>
#include <hip/hip_bf16.h>
#include <float.h>
#include <math.h>

#define N_NODES 1024
#define N_EDGES 524288
#define IN_C    64
#define HID_C   128
#define OUT_C   512
#define MLP_H   64
#define ADJ_WORDS 32   // 1024 bits per dst row

typedef __attribute__((ext_vector_type(8))) short short8;
typedef __attribute__((ext_vector_type(4))) float f32x4;

static __device__ __forceinline__ unsigned short f2bf(float f) {
    __hip_bfloat16 h = __float2bfloat16(f);
    return __builtin_bit_cast(unsigned short, h);
}

// ---------------------------------------------------------------------------
// adjacency bitmap build (dedup: max-agg is idempotent, duplicates collapse)
// ---------------------------------------------------------------------------
__global__ void k_zero_adj(unsigned int* __restrict__ adj) {
    int i = blockIdx.x * blockDim.x + threadIdx.x;
    if (i < N_NODES * ADJ_WORDS) adj[i] = 0u;
}

__global__ void k_build_adj(const int* __restrict__ ei, unsigned int* __restrict__ adj) {
    int e = blockIdx.x * blockDim.x + threadIdx.x;
    if (e >= N_EDGES) return;
    int src = ei[e];            // edge_index[0] = src
    int dst = ei[N_EDGES + e];  // edge_index[1] = dst
    atomicOr(&adj[dst * ADJ_WORDS + (src >> 5)], 1u << (src & 31));
}

// ---------------------------------------------------------------------------
// pack fp32 W[64][C] into bf16 MFMA B-fragments: Wpk[nt][kf][lane][8]
// lane l of n-tile nt, k-frag kf supplies W[kf*32 + (l>>4)*8 + e][nt*16 + (l&15)]
// ---------------------------------------------------------------------------
__global__ void k_pack_w(const float* __restrict__ W, unsigned short* __restrict__ Wpk, int C) {
    int idx = blockIdx.x * blockDim.x + threadIdx.x;
    int total = (C / 16) * 2 * 64;
    if (idx >= total) return;
    int lane = idx & 63;
    int kf = (idx >> 6) & 1;
    int nt = idx >> 7;
    int kbase = kf * 32 + (lane >> 4) * 8;
    int c = nt * 16 + (lane & 15);
#pragma unroll
    for (int e = 0; e < 8; ++e)
        Wpk[idx * 8 + e] = f2bf(W[(kbase + e) * C + c]);
}

// ---------------------------------------------------------------------------
// node transform 1: A1[n] = x[n] @ W1[0:64,:] + b1 ; B1[n] = x[n] @ W1[64:128,:]
// ---------------------------------------------------------------------------
__global__ void k_xform1(const float* __restrict__ x, const float* __restrict__ W1,
                         const float* __restrict__ b1,
                         float* __restrict__ A1, float* __restrict__ B1) {
    int n = blockIdx.x, t = threadIdx.x;  // 64 threads
    __shared__ float xs[IN_C];
    xs[t] = x[n * IN_C + t];
    __syncthreads();
    float a = b1[t], b = 0.f;
#pragma unroll
    for (int k = 0; k < IN_C; ++k) {
        float xv = xs[k];
        a = fmaf(xv, W1[k * MLP_H + t], a);
        b = fmaf(xv, W1[(IN_C + k) * MLP_H + t], b);
    }
    A1[n * MLP_H + t] = a;
    B1[n * MLP_H + t] = b;
}

// node transform 2: A2[n] = h1[n] @ W3[0:128,:] + b3 ; B2[n] = h1[n] @ W3[128:256,:]
__global__ void k_xform2(const float* __restrict__ h1, const float* __restrict__ W3,
                         const float* __restrict__ b3,
                         float* __restrict__ A2, float* __restrict__ B2) {
    int n = blockIdx.x, t = threadIdx.x;  // 64 threads
    __shared__ float hs[HID_C];
    hs[t] = h1[n * HID_C + t];
    hs[t + 64] = h1[n * HID_C + t + 64];
    __syncthreads();
    float a = b3[t], b = 0.f;
#pragma unroll
    for (int k = 0; k < HID_C; ++k) {
        float hv = hs[k];
        a = fmaf(hv, W3[k * MLP_H + t], a);
        b = fmaf(hv, W3[(HID_C + k) * MLP_H + t], b);
    }
    A2[n * MLP_H + t] = a;
    B2[n * MLP_H + t] = b;
}

// ---------------------------------------------------------------------------
// fused edge-MLP second layer + segment-max via MFMA bf16.
// One block (4 waves) per dst node. Each wave owns NTILES 16-channel tiles,
// W-fragments in registers. Per 16-edge tile: build bf16 A-frags of
// Z = relu(A[dst]+B[src]) in-register, 2 MFMA per n-tile (K=64), fold rows
// into a running max (rows union away -> only col mapping matters).
// Tail edges padded with duplicate of list[0] (max is idempotent).
// ---------------------------------------------------------------------------
template <int NTILES, int C_TOTAL>
__global__ __launch_bounds__(256) void k_conv_mfma(
        const unsigned int* __restrict__ adj,
        const float* __restrict__ Anode, const float* __restrict__ Bnode,
        const unsigned short* __restrict__ Wpk, const float* __restrict__ bias_g,
        float* __restrict__ out) {
    __shared__ unsigned short list[N_NODES + 16];
    __shared__ int cnt;
    const int i = blockIdx.x;
    const int tid = threadIdx.x;
    const int lane = tid & 63;
    const int wave = tid >> 6;   // 0..3
    const int g = lane >> 4;     // lane group 0..3
    const int r = lane & 15;     // row within edge-tile / col within out-tile

    if (tid == 0) cnt = 0;
    __syncthreads();
    // compact set bits of adjacency row into LDS list (order irrelevant for max)
    for (int w = tid; w < ADJ_WORDS; w += 256) {
        unsigned int bits = adj[i * ADJ_WORDS + w];
        while (bits) {
            int b = __ffs(bits) - 1;
            bits &= bits - 1;
            int pos = atomicAdd(&cnt, 1);
            list[pos] = (unsigned short)(w * 32 + b);
        }
    }
    __syncthreads();
    const int deg = cnt;

    if (deg == 0) {
        if (lane < 16) {
#pragma unroll
            for (int n = 0; n < NTILES; ++n)
                out[i * C_TOTAL + (wave * NTILES + n) * 16 + lane] = 0.f;
        }
        return;
    }

    const int padded = (deg + 15) & ~15;
    for (int p = deg + tid; p < padded; p += 256) list[p] = list[0];
    __syncthreads();

    // W fragments in registers (static indices via full unroll)
    short8 wfr[NTILES][2];
#pragma unroll
    for (int n = 0; n < NTILES; ++n) {
        int nt = wave * NTILES + n;
#pragma unroll
        for (int kf = 0; kf < 2; ++kf)
            wfr[n][kf] = ((const short8*)Wpk)[(nt * 2 + kf) * 64 + lane];
    }

    // A[dst] slices this lane needs (fp32): k = g*8..g*8+7 and 32+g*8..+7
    const f32x4* Ap = (const f32x4*)(Anode + i * MLP_H);
    f32x4 a0 = Ap[g * 2], a1 = Ap[g * 2 + 1], a2 = Ap[8 + g * 2], a3 = Ap[9 + g * 2];

    float mx[NTILES];
#pragma unroll
    for (int n = 0; n < NTILES; ++n) mx[n] = -INFINITY;

    const f32x4 zero = {0.f, 0.f, 0.f, 0.f};
    const int ntiles_e = padded >> 4;
    for (int t = 0; t < ntiles_e; ++t) {
        int j = list[t * 16 + r];
        const f32x4* Bp = (const f32x4*)(Bnode + j * MLP_H);
        f32x4 b0 = Bp[g * 2], b1 = Bp[g * 2 + 1], b2 = Bp[8 + g * 2], b3 = Bp[9 + g * 2];
        f32x4 s0 = a0 + b0, s1 = a1 + b1, s2 = a2 + b2, s3 = a3 + b3;
        short8 z0, z1;
#pragma unroll
        for (int e = 0; e < 4; ++e) {
            z0[e]     = (short)f2bf(fmaxf(s0[e], 0.f));
            z0[e + 4] = (short)f2bf(fmaxf(s1[e], 0.f));
            z1[e]     = (short)f2bf(fmaxf(s2[e], 0.f));
            z1[e + 4] = (short)f2bf(fmaxf(s3[e], 0.f));
        }
#pragma unroll
        for (int n = 0; n < NTILES; ++n) {
            f32x4 acc = __builtin_amdgcn_mfma_f32_16x16x32_bf16(z0, wfr[n][0], zero, 0, 0, 0);
            acc = __builtin_amdgcn_mfma_f32_16x16x32_bf16(z1, wfr[n][1], acc, 0, 0, 0);
            // D col = lane&15 (verified layout); rows are max-reduced away
            mx[n] = fmaxf(mx[n], fmaxf(fmaxf(acc[0], acc[1]), fmaxf(acc[2], acc[3])));
        }
    }

    // combine partial maxes across the 4 lane-groups (same col = lane&15)
#pragma unroll
    for (int n = 0; n < NTILES; ++n) {
        mx[n] = fmaxf(mx[n], __shfl_xor(mx[n], 16));
        mx[n] = fmaxf(mx[n], __shfl_xor(mx[n], 32));
    }
    if (lane < 16) {
#pragma unroll
        for (int n = 0; n < NTILES; ++n) {
            int c = (wave * NTILES + n) * 16 + lane;
            out[i * C_TOTAL + c] = mx[n] + bias_g[c];
        }
    }
}

// ---------------------------------------------------------------------------
// readout: out[c][o] = sum_n h2[n][c] * Wr[n][o] + br[o]   (512x1024 @ 1024x512)
// ---------------------------------------------------------------------------
__global__ __launch_bounds__(256) void k_readout(
        const float* __restrict__ h2, const float* __restrict__ Wr,
        const float* __restrict__ br, float* __restrict__ out) {
    __shared__ float At[64][65];  // At[c][k] (transposed h2 tile)
    __shared__ float Bt[64][65];  // Bt[k][o]
    const int c0 = (blockIdx.x / 8) * 64;
    const int o0 = (blockIdx.x % 8) * 64;
    const int tid = threadIdx.x;
    const int tx = tid % 16, ty = tid / 16;
    float acc[4][4] = {};
    for (int k0 = 0; k0 < N_NODES; k0 += 64) {
        for (int s = tid; s < 64 * 64; s += 256) {
            int r = s / 64, cc = s % 64;
            At[cc][r] = h2[(k0 + r) * OUT_C + c0 + cc];
            Bt[r][cc] = Wr[(k0 + r) * OUT_C + o0 + cc];
        }
        __syncthreads();
#pragma unroll 8
        for (int kk = 0; kk < 64; ++kk) {
            float a[4], b[4];
#pragma unroll
            for (int u = 0; u < 4; ++u) a[u] = At[ty * 4 + u][kk];
#pragma unroll
            for (int v = 0; v < 4; ++v) b[v] = Bt[kk][tx * 4 + v];
#pragma unroll
            for (int u = 0; u < 4; ++u)
#pragma unroll
                for (int v = 0; v < 4; ++v) acc[u][v] = fmaf(a[u], b[v], acc[u][v]);
        }
        __syncthreads();
    }
#pragma unroll
    for (int u = 0; u < 4; ++u)
#pragma unroll
        for (int v = 0; v < 4; ++v)
            out[(c0 + ty * 4 + u) * OUT_C + (o0 + tx * 4 + v)] = acc[u][v] + br[o0 + tx * 4 + v];
}

// ---------------------------------------------------------------------------
extern "C" void kernel_launch(void* const* d_in, const int* in_sizes, int n_in,
                              void* d_out, int out_size, void* d_ws, size_t ws_size,
                              hipStream_t stream) {
    const float* x  = (const float*)d_in[0];
    const int*   ei = (const int*)d_in[1];
    const float* W1 = (const float*)d_in[2];
    const float* b1 = (const float*)d_in[3];
    const float* W2 = (const float*)d_in[4];
    const float* b2 = (const float*)d_in[5];
    const float* W3 = (const float*)d_in[6];
    const float* b3 = (const float*)d_in[7];
    const float* W4 = (const float*)d_in[8];
    const float* b4 = (const float*)d_in[9];
    const float* Wr = (const float*)d_in[10];
    const float* br = (const float*)d_in[11];
    float* out = (float*)d_out;

    // workspace partition (all 256B-aligned)
    char* ws = (char*)d_ws;
    unsigned int* adj = (unsigned int*)ws;                 // 131072 B
    float* A1 = (float*)(ws + 131072);                     // 262144 B
    float* B1 = (float*)(ws + 393216);                     // 262144 B
    float* h1 = (float*)(ws + 655360);                     // 524288 B
    float* A2 = (float*)(ws + 1179648);                    // 262144 B
    float* B2 = (float*)(ws + 1441792);                    // 262144 B
    float* h2 = (float*)(ws + 1703936);                    // 2097152 B
    unsigned short* Wpk1 = (unsigned short*)(ws + 3801088); // 16384 B  (128/16*2*64*8*2)
    unsigned short* Wpk2 = (unsigned short*)(ws + 3817472); // 65536 B  (512/16*2*64*8*2)
    // total 3883008 B

    k_zero_adj<<<dim3((N_NODES * ADJ_WORDS + 255) / 256), dim3(256), 0, stream>>>(adj);
    k_build_adj<<<dim3(N_EDGES / 256), dim3(256), 0, stream>>>(ei, adj);
    k_pack_w<<<dim3(4), dim3(256), 0, stream>>>(W2, Wpk1, HID_C);
    k_pack_w<<<dim3(16), dim3(256), 0, stream>>>(W4, Wpk2, OUT_C);
    k_xform1<<<dim3(N_NODES), dim3(64), 0, stream>>>(x, W1, b1, A1, B1);
    k_conv_mfma<2, HID_C><<<dim3(N_NODES), dim3(256), 0, stream>>>(adj, A1, B1, Wpk1, b2, h1);
    k_xform2<<<dim3(N_NODES), dim3(64), 0, stream>>>(h1, W3, b3, A2, B2);
    k_conv_mfma<8, OUT_C><<<dim3(N_NODES), dim3(256), 0, stream>>>(adj, A2, B2, Wpk2, b4, h2);
    k_readout<<<dim3(64), dim3(256), 0, stream>>>(h2, Wr, br, out);
}

// Round 3
// 241.932 us; speedup vs baseline: 3.3341x; 1.1875x over previous
//
#include <hip/hip_runtime.h>
#include <hip/hip_bf16.h>
#include <float.h>
#include <math.h>

#define N_NODES 1024
#define N_EDGES 524288
#define IN_C    64
#define HID_C   128
#define OUT_C   512
#define MLP_H   64
#define ADJ_WORDS 32   // 1024 bits per dst row
#define KSPLIT  4
#define KCHUNK  (N_NODES / KSPLIT)  // 256

typedef __attribute__((ext_vector_type(8))) short short8;
typedef __attribute__((ext_vector_type(4))) float f32x4;

static __device__ __forceinline__ unsigned short f2bf(float f) {
    __hip_bfloat16 h = __float2bfloat16(f);
    return __builtin_bit_cast(unsigned short, h);
}

// ---------------------------------------------------------------------------
// adjacency bitmap build (dedup: max-agg is idempotent, duplicates collapse)
// ---------------------------------------------------------------------------
__global__ void k_zero_adj(unsigned int* __restrict__ adj) {
    int i = blockIdx.x * blockDim.x + threadIdx.x;
    if (i < N_NODES * ADJ_WORDS) adj[i] = 0u;
}

__global__ void k_build_adj(const int* __restrict__ ei, unsigned int* __restrict__ adj) {
    int e = blockIdx.x * blockDim.x + threadIdx.x;
    if (e >= N_EDGES) return;
    int src = ei[e];            // edge_index[0] = src
    int dst = ei[N_EDGES + e];  // edge_index[1] = dst
    atomicOr(&adj[dst * ADJ_WORDS + (src >> 5)], 1u << (src & 31));
}

// ---------------------------------------------------------------------------
// pack fp32 W[64][C] into bf16 MFMA B-fragments: Wpk[nt][kf][lane][8]
// lane l of n-tile nt, k-frag kf supplies W[kf*32 + (l>>4)*8 + e][nt*16 + (l&15)]
// ---------------------------------------------------------------------------
__global__ void k_pack_w(const float* __restrict__ W, unsigned short* __restrict__ Wpk, int C) {
    int idx = blockIdx.x * blockDim.x + threadIdx.x;
    int total = (C / 16) * 2 * 64;
    if (idx >= total) return;
    int lane = idx & 63;
    int kf = (idx >> 6) & 1;
    int nt = idx >> 7;
    int kbase = kf * 32 + (lane >> 4) * 8;
    int c = nt * 16 + (lane & 15);
#pragma unroll
    for (int e = 0; e < 8; ++e)
        Wpk[idx * 8 + e] = f2bf(W[(kbase + e) * C + c]);
}

// ---------------------------------------------------------------------------
// node transform 1: A1[n] = x[n] @ W1[0:64,:] + b1 ; B1[n] = x[n] @ W1[64:128,:]
// ---------------------------------------------------------------------------
__global__ void k_xform1(const float* __restrict__ x, const float* __restrict__ W1,
                         const float* __restrict__ b1,
                         float* __restrict__ A1, float* __restrict__ B1) {
    int n = blockIdx.x, t = threadIdx.x;  // 64 threads
    __shared__ float xs[IN_C];
    xs[t] = x[n * IN_C + t];
    __syncthreads();
    float a = b1[t], b = 0.f;
#pragma unroll
    for (int k = 0; k < IN_C; ++k) {
        float xv = xs[k];
        a = fmaf(xv, W1[k * MLP_H + t], a);
        b = fmaf(xv, W1[(IN_C + k) * MLP_H + t], b);
    }
    A1[n * MLP_H + t] = a;
    B1[n * MLP_H + t] = b;
}

// node transform 2: A2[n] = h1[n] @ W3[0:128,:] + b3 ; B2[n] = h1[n] @ W3[128:256,:]
__global__ void k_xform2(const float* __restrict__ h1, const float* __restrict__ W3,
                         const float* __restrict__ b3,
                         float* __restrict__ A2, float* __restrict__ B2) {
    int n = blockIdx.x, t = threadIdx.x;  // 64 threads
    __shared__ float hs[HID_C];
    hs[t] = h1[n * HID_C + t];
    hs[t + 64] = h1[n * HID_C + t + 64];
    __syncthreads();
    float a = b3[t], b = 0.f;
#pragma unroll
    for (int k = 0; k < HID_C; ++k) {
        float hv = hs[k];
        a = fmaf(hv, W3[k * MLP_H + t], a);
        b = fmaf(hv, W3[(HID_C + k) * MLP_H + t], b);
    }
    A2[n * MLP_H + t] = a;
    B2[n * MLP_H + t] = b;
}

// ---------------------------------------------------------------------------
// fused edge-MLP second layer + segment-max via MFMA bf16.
// One block (4 waves) per dst node. Each wave owns NTILES 16-channel tiles,
// W-fragments in registers. Per 16-edge tile: build bf16 A-frags of
// Z = relu(A[dst]+B[src]) in-register, 2 MFMA per n-tile (K=64), fold rows
// into a running max (rows union away -> only col mapping matters).
// Tail edges padded with duplicate of list[0] (max is idempotent).
// ---------------------------------------------------------------------------
template <int NTILES, int C_TOTAL>
__global__ __launch_bounds__(256) void k_conv_mfma(
        const unsigned int* __restrict__ adj,
        const float* __restrict__ Anode, const float* __restrict__ Bnode,
        const unsigned short* __restrict__ Wpk, const float* __restrict__ bias_g,
        float* __restrict__ out) {
    __shared__ unsigned short list[N_NODES + 16];
    __shared__ int cnt;
    const int i = blockIdx.x;
    const int tid = threadIdx.x;
    const int lane = tid & 63;
    const int wave = tid >> 6;   // 0..3
    const int g = lane >> 4;     // lane group 0..3
    const int r = lane & 15;     // row within edge-tile / col within out-tile

    if (tid == 0) cnt = 0;
    __syncthreads();
    // compact set bits of adjacency row into LDS list (order irrelevant for max)
    for (int w = tid; w < ADJ_WORDS; w += 256) {
        unsigned int bits = adj[i * ADJ_WORDS + w];
        while (bits) {
            int b = __ffs(bits) - 1;
            bits &= bits - 1;
            int pos = atomicAdd(&cnt, 1);
            list[pos] = (unsigned short)(w * 32 + b);
        }
    }
    __syncthreads();
    const int deg = cnt;

    if (deg == 0) {
        if (lane < 16) {
#pragma unroll
            for (int n = 0; n < NTILES; ++n)
                out[i * C_TOTAL + (wave * NTILES + n) * 16 + lane] = 0.f;
        }
        return;
    }

    const int padded = (deg + 15) & ~15;
    for (int p = deg + tid; p < padded; p += 256) list[p] = list[0];
    __syncthreads();

    // W fragments in registers (static indices via full unroll)
    short8 wfr[NTILES][2];
#pragma unroll
    for (int n = 0; n < NTILES; ++n) {
        int nt = wave * NTILES + n;
#pragma unroll
        for (int kf = 0; kf < 2; ++kf)
            wfr[n][kf] = ((const short8*)Wpk)[(nt * 2 + kf) * 64 + lane];
    }

    // A[dst] slices this lane needs (fp32): k = g*8..g*8+7 and 32+g*8..+7
    const f32x4* Ap = (const f32x4*)(Anode + i * MLP_H);
    f32x4 a0 = Ap[g * 2], a1 = Ap[g * 2 + 1], a2 = Ap[8 + g * 2], a3 = Ap[9 + g * 2];

    float mx[NTILES];
#pragma unroll
    for (int n = 0; n < NTILES; ++n) mx[n] = -INFINITY;

    const f32x4 zero = {0.f, 0.f, 0.f, 0.f};
    const int ntiles_e = padded >> 4;
    for (int t = 0; t < ntiles_e; ++t) {
        int j = list[t * 16 + r];
        const f32x4* Bp = (const f32x4*)(Bnode + j * MLP_H);
        f32x4 b0 = Bp[g * 2], b1 = Bp[g * 2 + 1], b2 = Bp[8 + g * 2], b3 = Bp[9 + g * 2];
        f32x4 s0 = a0 + b0, s1 = a1 + b1, s2 = a2 + b2, s3 = a3 + b3;
        short8 z0, z1;
#pragma unroll
        for (int e = 0; e < 4; ++e) {
            z0[e]     = (short)f2bf(fmaxf(s0[e], 0.f));
            z0[e + 4] = (short)f2bf(fmaxf(s1[e], 0.f));
            z1[e]     = (short)f2bf(fmaxf(s2[e], 0.f));
            z1[e + 4] = (short)f2bf(fmaxf(s3[e], 0.f));
        }
#pragma unroll
        for (int n = 0; n < NTILES; ++n) {
            f32x4 acc = __builtin_amdgcn_mfma_f32_16x16x32_bf16(z0, wfr[n][0], zero, 0, 0, 0);
            acc = __builtin_amdgcn_mfma_f32_16x16x32_bf16(z1, wfr[n][1], acc, 0, 0, 0);
            // D col = lane&15 (verified layout); rows are max-reduced away
            mx[n] = fmaxf(mx[n], fmaxf(fmaxf(acc[0], acc[1]), fmaxf(acc[2], acc[3])));
        }
    }

    // combine partial maxes across the 4 lane-groups (same col = lane&15)
#pragma unroll
    for (int n = 0; n < NTILES; ++n) {
        mx[n] = fmaxf(mx[n], __shfl_xor(mx[n], 16));
        mx[n] = fmaxf(mx[n], __shfl_xor(mx[n], 32));
    }
    if (lane < 16) {
#pragma unroll
        for (int n = 0; n < NTILES; ++n) {
            int c = (wave * NTILES + n) * 16 + lane;
            out[i * C_TOTAL + c] = mx[n] + bias_g[c];
        }
    }
}

// ---------------------------------------------------------------------------
// readout split-K partials: partial[kc][c][o] = sum_{n in chunk} h2[n][c]*Wr[n][o]
// grid = 64 tiles * KSPLIT; block 256 = 16x16 threads, 4x4 regs each.
// As[k][c] / Bs[k][o] are direct coalesced copies (no transpose).
// ---------------------------------------------------------------------------
__global__ __launch_bounds__(256) void k_readout_part(
        const float* __restrict__ h2, const float* __restrict__ Wr,
        float* __restrict__ partial) {
    __shared__ float As[64][64];
    __shared__ float Bs[64][64];
    const int bid = blockIdx.x;
    const int kc = bid >> 6;
    const int c0 = ((bid >> 3) & 7) * 64;
    const int o0 = (bid & 7) * 64;
    const int k0 = kc * KCHUNK;
    const int tid = threadIdx.x;
    const int tx = tid & 15, ty = tid >> 4;
    float acc[4][4] = {};
    for (int ks = 0; ks < KCHUNK; ks += 64) {
        for (int s = tid; s < 1024; s += 256) {
            int rr = s >> 4;
            int cq = (s & 15) * 4;
            *(float4*)&As[rr][cq] = *(const float4*)&h2[(k0 + ks + rr) * OUT_C + c0 + cq];
            *(float4*)&Bs[rr][cq] = *(const float4*)&Wr[(k0 + ks + rr) * OUT_C + o0 + cq];
        }
        __syncthreads();
#pragma unroll 16
        for (int kk = 0; kk < 64; ++kk) {
            float4 a = *(float4*)&As[kk][ty * 4];
            float4 b = *(float4*)&Bs[kk][tx * 4];
            acc[0][0] = fmaf(a.x, b.x, acc[0][0]); acc[0][1] = fmaf(a.x, b.y, acc[0][1]);
            acc[0][2] = fmaf(a.x, b.z, acc[0][2]); acc[0][3] = fmaf(a.x, b.w, acc[0][3]);
            acc[1][0] = fmaf(a.y, b.x, acc[1][0]); acc[1][1] = fmaf(a.y, b.y, acc[1][1]);
            acc[1][2] = fmaf(a.y, b.z, acc[1][2]); acc[1][3] = fmaf(a.y, b.w, acc[1][3]);
            acc[2][0] = fmaf(a.z, b.x, acc[2][0]); acc[2][1] = fmaf(a.z, b.y, acc[2][1]);
            acc[2][2] = fmaf(a.z, b.z, acc[2][2]); acc[2][3] = fmaf(a.z, b.w, acc[2][3]);
            acc[3][0] = fmaf(a.w, b.x, acc[3][0]); acc[3][1] = fmaf(a.w, b.y, acc[3][1]);
            acc[3][2] = fmaf(a.w, b.z, acc[3][2]); acc[3][3] = fmaf(a.w, b.w, acc[3][3]);
        }
        __syncthreads();
    }
    float* pb = partial + kc * (OUT_C * OUT_C);
#pragma unroll
    for (int u = 0; u < 4; ++u) {
        float4 v = {acc[u][0], acc[u][1], acc[u][2], acc[u][3]};
        *(float4*)&pb[(c0 + ty * 4 + u) * OUT_C + o0 + tx * 4] = v;
    }
}

// reduce KSPLIT partials + bias -> out
__global__ __launch_bounds__(256) void k_readout_reduce(
        const float* __restrict__ partial, const float* __restrict__ br,
        float* __restrict__ out) {
    int i = blockIdx.x * 256 + threadIdx.x;  // float4 index, 65536 total
    const float4* p4 = (const float4*)partial;
    float4 s = p4[i];
    float4 t1 = p4[i + 65536];
    float4 t2 = p4[i + 131072];
    float4 t3 = p4[i + 196608];
    s.x += t1.x + t2.x + t3.x;
    s.y += t1.y + t2.y + t3.y;
    s.z += t1.z + t2.z + t3.z;
    s.w += t1.w + t2.w + t3.w;
    float4 b = ((const float4*)br)[i & 127];
    s.x += b.x; s.y += b.y; s.z += b.z; s.w += b.w;
    ((float4*)out)[i] = s;
}

// ---------------------------------------------------------------------------
extern "C" void kernel_launch(void* const* d_in, const int* in_sizes, int n_in,
                              void* d_out, int out_size, void* d_ws, size_t ws_size,
                              hipStream_t stream) {
    const float* x  = (const float*)d_in[0];
    const int*   ei = (const int*)d_in[1];
    const float* W1 = (const float*)d_in[2];
    const float* b1 = (const float*)d_in[3];
    const float* W2 = (const float*)d_in[4];
    const float* b2 = (const float*)d_in[5];
    const float* W3 = (const float*)d_in[6];
    const float* b3 = (const float*)d_in[7];
    const float* W4 = (const float*)d_in[8];
    const float* b4 = (const float*)d_in[9];
    const float* Wr = (const float*)d_in[10];
    const float* br = (const float*)d_in[11];
    float* out = (float*)d_out;

    // workspace partition (all 256B-aligned)
    char* ws = (char*)d_ws;
    unsigned int* adj = (unsigned int*)ws;                 // 131072 B
    float* A1 = (float*)(ws + 131072);                     // 262144 B
    float* B1 = (float*)(ws + 393216);                     // 262144 B
    float* h1 = (float*)(ws + 655360);                     // 524288 B
    float* A2 = (float*)(ws + 1179648);                    // 262144 B
    float* B2 = (float*)(ws + 1441792);                    // 262144 B
    float* h2 = (float*)(ws + 1703936);                    // 2097152 B
    unsigned short* Wpk1 = (unsigned short*)(ws + 3801088); // 16384 B
    unsigned short* Wpk2 = (unsigned short*)(ws + 3817472); // 65536 B
    float* partial = (float*)(ws + 3883008);               // 4194304 B (KSPLIT=4 x 1MB)
    // total 8077312 B

    k_zero_adj<<<dim3((N_NODES * ADJ_WORDS + 255) / 256), dim3(256), 0, stream>>>(adj);
    k_build_adj<<<dim3(N_EDGES / 256), dim3(256), 0, stream>>>(ei, adj);
    k_pack_w<<<dim3(4), dim3(256), 0, stream>>>(W2, Wpk1, HID_C);
    k_pack_w<<<dim3(16), dim3(256), 0, stream>>>(W4, Wpk2, OUT_C);
    k_xform1<<<dim3(N_NODES), dim3(64), 0, stream>>>(x, W1, b1, A1, B1);
    k_conv_mfma<2, HID_C><<<dim3(N_NODES), dim3(256), 0, stream>>>(adj, A1, B1, Wpk1, b2, h1);
    k_xform2<<<dim3(N_NODES), dim3(64), 0, stream>>>(h1, W3, b3, A2, B2);
    k_conv_mfma<8, OUT_C><<<dim3(N_NODES), dim3(256), 0, stream>>>(adj, A2, B2, Wpk2, b4, h2);
    k_readout_part<<<dim3(64 * KSPLIT), dim3(256), 0, stream>>>(h2, Wr, partial);
    k_readout_reduce<<<dim3(256), dim3(256), 0, stream>>>(partial, br, out);
}

// Round 4
// 185.079 us; speedup vs baseline: 4.3583x; 1.3072x over previous
//
#include <hip/hip_runtime.h>
#include <hip/hip_bf16.h>
#include <float.h>
#include <math.h>

#define N_NODES 1024
#define N_EDGES 524288
#define IN_C    64
#define HID_C   128
#define OUT_C   512
#define MLP_H   64
#define ADJ_WORDS 32   // 1024 bits per dst row
#define KSPLIT  4
#define KCHUNK  (N_NODES / KSPLIT)  // 256

typedef __attribute__((ext_vector_type(8))) short short8;
typedef __attribute__((ext_vector_type(4))) float f32x4;

static __device__ __forceinline__ unsigned short f2bf(float f) {
    __hip_bfloat16 h = __float2bfloat16(f);
    return __builtin_bit_cast(unsigned short, h);
}

// ---------------------------------------------------------------------------
// adjacency bitmap build (dedup: max-agg is idempotent, duplicates collapse)
// ---------------------------------------------------------------------------
__global__ void k_zero_adj(unsigned int* __restrict__ adj) {
    int i = blockIdx.x * blockDim.x + threadIdx.x;
    if (i < N_NODES * ADJ_WORDS) adj[i] = 0u;
}

__global__ void k_build_adj(const int* __restrict__ ei, unsigned int* __restrict__ adj) {
    int e = blockIdx.x * blockDim.x + threadIdx.x;
    if (e >= N_EDGES) return;
    int src = ei[e];            // edge_index[0] = src
    int dst = ei[N_EDGES + e];  // edge_index[1] = dst
    atomicOr(&adj[dst * ADJ_WORDS + (src >> 5)], 1u << (src & 31));
}

// ---------------------------------------------------------------------------
// pack fp32 W[64][C] into bf16 MFMA B-fragments: Wpk[nt][kf][lane][8]
// lane l of n-tile nt, k-frag kf supplies W[kf*32 + (l>>4)*8 + e][nt*16 + (l&15)]
// ---------------------------------------------------------------------------
__global__ void k_pack_w(const float* __restrict__ W, unsigned short* __restrict__ Wpk, int C) {
    int idx = blockIdx.x * blockDim.x + threadIdx.x;
    int total = (C / 16) * 2 * 64;
    if (idx >= total) return;
    int lane = idx & 63;
    int kf = (idx >> 6) & 1;
    int nt = idx >> 7;
    int kbase = kf * 32 + (lane >> 4) * 8;
    int c = nt * 16 + (lane & 15);
#pragma unroll
    for (int e = 0; e < 8; ++e)
        Wpk[idx * 8 + e] = f2bf(W[(kbase + e) * C + c]);
}

// ---------------------------------------------------------------------------
// node transform 1: A1[n] = x[n] @ W1[0:64,:] + b1 ; B1[n] = x[n] @ W1[64:128,:]
// ---------------------------------------------------------------------------
__global__ void k_xform1(const float* __restrict__ x, const float* __restrict__ W1,
                         const float* __restrict__ b1,
                         float* __restrict__ A1, float* __restrict__ B1) {
    int n = blockIdx.x, t = threadIdx.x;  // 64 threads
    __shared__ float xs[IN_C];
    xs[t] = x[n * IN_C + t];
    __syncthreads();
    float a = b1[t], b = 0.f;
#pragma unroll
    for (int k = 0; k < IN_C; ++k) {
        float xv = xs[k];
        a = fmaf(xv, W1[k * MLP_H + t], a);
        b = fmaf(xv, W1[(IN_C + k) * MLP_H + t], b);
    }
    A1[n * MLP_H + t] = a;
    B1[n * MLP_H + t] = b;
}

// node transform 2: A2[n] = h1[n] @ W3[0:128,:] + b3 ; B2[n] = h1[n] @ W3[128:256,:]
__global__ void k_xform2(const float* __restrict__ h1, const float* __restrict__ W3,
                         const float* __restrict__ b3,
                         float* __restrict__ A2, float* __restrict__ B2) {
    int n = blockIdx.x, t = threadIdx.x;  // 64 threads
    __shared__ float hs[HID_C];
    hs[t] = h1[n * HID_C + t];
    hs[t + 64] = h1[n * HID_C + t + 64];
    __syncthreads();
    float a = b3[t], b = 0.f;
#pragma unroll
    for (int k = 0; k < HID_C; ++k) {
        float hv = hs[k];
        a = fmaf(hv, W3[k * MLP_H + t], a);
        b = fmaf(hv, W3[(HID_C + k) * MLP_H + t], b);
    }
    A2[n * MLP_H + t] = a;
    B2[n * MLP_H + t] = b;
}

// ---------------------------------------------------------------------------
// fused edge-MLP second layer + segment-max via MFMA bf16, cooperative build.
// One block (4 waves) per dst node. Per batch of 4 edge-tiles: each wave
// builds ONE tile's bf16 A-fragments (z = relu(A[dst]+B[src])) into LDS
// (double-buffered, MFMA fragment layout, 16B/lane contiguous), then ALL
// waves consume all tiles with their register-resident W-fragments.
// z-build cost: once per block (was 4x, once per wave).
// Tail edges padded with duplicate of list[0] (max is idempotent).
// ---------------------------------------------------------------------------
template <int NTILES, int C_TOTAL>
__global__ __launch_bounds__(256, (NTILES == 2 ? 5 : 4)) void k_conv_mfma(
        const unsigned int* __restrict__ adj,
        const float* __restrict__ Anode, const float* __restrict__ Bnode,
        const unsigned short* __restrict__ Wpk, const float* __restrict__ bias_g,
        float* __restrict__ out) {
    constexpr int BATCH = 4;  // edge-tiles per batch (1 per wave)
    __shared__ unsigned short list[N_NODES + 16];
    __shared__ short8 zbuf[2][BATCH][2][64];  // [dbuf][tile][kfrag][lane] 16 KB
    __shared__ int cnt;
    const int i = blockIdx.x;
    const int tid = threadIdx.x;
    const int lane = tid & 63;
    const int wave = tid >> 6;   // 0..3
    const int g = lane >> 4;     // lane group 0..3
    const int r = lane & 15;     // row within edge-tile / col within out-tile

    // wave 0: popcount prefix-scan compaction of adjacency row (no atomics)
    if (wave == 0) {
        unsigned int bits = (lane < ADJ_WORDS) ? adj[i * ADJ_WORDS + lane] : 0u;
        int c = __popc(bits);
        int pre = c;
#pragma unroll
        for (int d = 1; d < 64; d <<= 1) {
            int t = __shfl_up(pre, d);
            if (lane >= d) pre += t;
        }
        int total = __shfl(pre, 63);
        int pos = pre - c + lane * 0;  // exclusive start
        while (bits) {
            int b = __ffs(bits) - 1;
            bits &= bits - 1;
            list[pos++] = (unsigned short)(lane * 32 + b);
        }
        if (lane == 0) cnt = total;
    }
    __syncthreads();
    const int deg = cnt;

    if (deg == 0) {
        if (lane < 16) {
#pragma unroll
            for (int n = 0; n < NTILES; ++n)
                out[i * C_TOTAL + (wave * NTILES + n) * 16 + lane] = 0.f;
        }
        return;
    }

    const int padded = (deg + 15) & ~15;
    for (int p = deg + tid; p < padded; p += 256) list[p] = list[0];

    // W fragments in registers (static indices via full unroll)
    short8 wfr[NTILES][2];
#pragma unroll
    for (int n = 0; n < NTILES; ++n) {
        int nt = wave * NTILES + n;
#pragma unroll
        for (int kf = 0; kf < 2; ++kf)
            wfr[n][kf] = ((const short8*)Wpk)[(nt * 2 + kf) * 64 + lane];
    }

    // A[dst] slices this lane needs (fp32): k = g*8..g*8+7 and 32+g*8..+7
    const f32x4* Ap = (const f32x4*)(Anode + i * MLP_H);
    f32x4 a0 = Ap[g * 2], a1 = Ap[g * 2 + 1], a2 = Ap[8 + g * 2], a3 = Ap[9 + g * 2];

    float mx[NTILES];
#pragma unroll
    for (int n = 0; n < NTILES; ++n) mx[n] = -INFINITY;

    // build ONE edge-tile (index base_tile+wave) into zbuf[buf][wave]
    auto build = [&](int buf, int base_tile, int ntl) {
        if (wave < ntl) {
            int j = list[(base_tile + wave) * 16 + r];
            const f32x4* Bp = (const f32x4*)(Bnode + (size_t)j * MLP_H);
            f32x4 b0 = Bp[g * 2], b1 = Bp[g * 2 + 1], b2 = Bp[8 + g * 2], b3 = Bp[9 + g * 2];
            f32x4 s0 = a0 + b0, s1 = a1 + b1, s2 = a2 + b2, s3 = a3 + b3;
            short8 z0, z1;
#pragma unroll
            for (int e = 0; e < 4; ++e) {
                z0[e]     = (short)f2bf(fmaxf(s0[e], 0.f));
                z0[e + 4] = (short)f2bf(fmaxf(s1[e], 0.f));
                z1[e]     = (short)f2bf(fmaxf(s2[e], 0.f));
                z1[e + 4] = (short)f2bf(fmaxf(s3[e], 0.f));
            }
            zbuf[buf][wave][0][lane] = z0;
            zbuf[buf][wave][1][lane] = z1;
        }
    };

    const int ntiles_e = padded >> 4;
    const f32x4 zero = {0.f, 0.f, 0.f, 0.f};

    __syncthreads();  // padding + list visible
    build(0, 0, min(BATCH, ntiles_e));
    __syncthreads();  // zbuf[0] ready

    int cur = 0;
    for (int b0 = 0; b0 < ntiles_e; b0 += BATCH) {
        int nb = min(BATCH, ntiles_e - b0);
        int nxt = b0 + BATCH;
        if (nxt < ntiles_e) build(cur ^ 1, nxt, min(BATCH, ntiles_e - nxt));
        for (int tt = 0; tt < nb; ++tt) {
            short8 z0 = zbuf[cur][tt][0][lane];
            short8 z1 = zbuf[cur][tt][1][lane];
#pragma unroll
            for (int n = 0; n < NTILES; ++n) {
                f32x4 acc = __builtin_amdgcn_mfma_f32_16x16x32_bf16(z0, wfr[n][0], zero, 0, 0, 0);
                acc = __builtin_amdgcn_mfma_f32_16x16x32_bf16(z1, wfr[n][1], acc, 0, 0, 0);
                // D col = lane&15 (verified layout); rows are max-reduced away
                mx[n] = fmaxf(mx[n], fmaxf(fmaxf(acc[0], acc[1]), fmaxf(acc[2], acc[3])));
            }
        }
        __syncthreads();
        cur ^= 1;
    }

    // combine partial maxes across the 4 lane-groups (same col = lane&15)
#pragma unroll
    for (int n = 0; n < NTILES; ++n) {
        mx[n] = fmaxf(mx[n], __shfl_xor(mx[n], 16));
        mx[n] = fmaxf(mx[n], __shfl_xor(mx[n], 32));
    }
    if (lane < 16) {
#pragma unroll
        for (int n = 0; n < NTILES; ++n) {
            int c = (wave * NTILES + n) * 16 + lane;
            out[i * C_TOTAL + c] = mx[n] + bias_g[c];
        }
    }
}

// ---------------------------------------------------------------------------
// readout split-K partials: partial[kc][c][o] = sum_{n in chunk} h2[n][c]*Wr[n][o]
// ---------------------------------------------------------------------------
__global__ __launch_bounds__(256) void k_readout_part(
        const float* __restrict__ h2, const float* __restrict__ Wr,
        float* __restrict__ partial) {
    __shared__ float As[64][64];
    __shared__ float Bs[64][64];
    const int bid = blockIdx.x;
    const int kc = bid >> 6;
    const int c0 = ((bid >> 3) & 7) * 64;
    const int o0 = (bid & 7) * 64;
    const int k0 = kc * KCHUNK;
    const int tid = threadIdx.x;
    const int tx = tid & 15, ty = tid >> 4;
    float acc[4][4] = {};
    for (int ks = 0; ks < KCHUNK; ks += 64) {
        for (int s = tid; s < 1024; s += 256) {
            int rr = s >> 4;
            int cq = (s & 15) * 4;
            *(float4*)&As[rr][cq] = *(const float4*)&h2[(k0 + ks + rr) * OUT_C + c0 + cq];
            *(float4*)&Bs[rr][cq] = *(const float4*)&Wr[(k0 + ks + rr) * OUT_C + o0 + cq];
        }
        __syncthreads();
#pragma unroll 16
        for (int kk = 0; kk < 64; ++kk) {
            float4 a = *(float4*)&As[kk][ty * 4];
            float4 b = *(float4*)&Bs[kk][tx * 4];
            acc[0][0] = fmaf(a.x, b.x, acc[0][0]); acc[0][1] = fmaf(a.x, b.y, acc[0][1]);
            acc[0][2] = fmaf(a.x, b.z, acc[0][2]); acc[0][3] = fmaf(a.x, b.w, acc[0][3]);
            acc[1][0] = fmaf(a.y, b.x, acc[1][0]); acc[1][1] = fmaf(a.y, b.y, acc[1][1]);
            acc[1][2] = fmaf(a.y, b.z, acc[1][2]); acc[1][3] = fmaf(a.y, b.w, acc[1][3]);
            acc[2][0] = fmaf(a.z, b.x, acc[2][0]); acc[2][1] = fmaf(a.z, b.y, acc[2][1]);
            acc[2][2] = fmaf(a.z, b.z, acc[2][2]); acc[2][3] = fmaf(a.z, b.w, acc[2][3]);
            acc[3][0] = fmaf(a.w, b.x, acc[3][0]); acc[3][1] = fmaf(a.w, b.y, acc[3][1]);
            acc[3][2] = fmaf(a.w, b.z, acc[3][2]); acc[3][3] = fmaf(a.w, b.w, acc[3][3]);
        }
        __syncthreads();
    }
    float* pb = partial + kc * (OUT_C * OUT_C);
#pragma unroll
    for (int u = 0; u < 4; ++u) {
        float4 v = {acc[u][0], acc[u][1], acc[u][2], acc[u][3]};
        *(float4*)&pb[(c0 + ty * 4 + u) * OUT_C + o0 + tx * 4] = v;
    }
}

// reduce KSPLIT partials + bias -> out
__global__ __launch_bounds__(256) void k_readout_reduce(
        const float* __restrict__ partial, const float* __restrict__ br,
        float* __restrict__ out) {
    int i = blockIdx.x * 256 + threadIdx.x;  // float4 index, 65536 total
    const float4* p4 = (const float4*)partial;
    float4 s = p4[i];
    float4 t1 = p4[i + 65536];
    float4 t2 = p4[i + 131072];
    float4 t3 = p4[i + 196608];
    s.x += t1.x + t2.x + t3.x;
    s.y += t1.y + t2.y + t3.y;
    s.z += t1.z + t2.z + t3.z;
    s.w += t1.w + t2.w + t3.w;
    float4 b = ((const float4*)br)[i & 127];
    s.x += b.x; s.y += b.y; s.z += b.z; s.w += b.w;
    ((float4*)out)[i] = s;
}

// ---------------------------------------------------------------------------
extern "C" void kernel_launch(void* const* d_in, const int* in_sizes, int n_in,
                              void* d_out, int out_size, void* d_ws, size_t ws_size,
                              hipStream_t stream) {
    const float* x  = (const float*)d_in[0];
    const int*   ei = (const int*)d_in[1];
    const float* W1 = (const float*)d_in[2];
    const float* b1 = (const float*)d_in[3];
    const float* W2 = (const float*)d_in[4];
    const float* b2 = (const float*)d_in[5];
    const float* W3 = (const float*)d_in[6];
    const float* b3 = (const float*)d_in[7];
    const float* W4 = (const float*)d_in[8];
    const float* b4 = (const float*)d_in[9];
    const float* Wr = (const float*)d_in[10];
    const float* br = (const float*)d_in[11];
    float* out = (float*)d_out;

    // workspace partition (all 256B-aligned)
    char* ws = (char*)d_ws;
    unsigned int* adj = (unsigned int*)ws;                 // 131072 B
    float* A1 = (float*)(ws + 131072);                     // 262144 B
    float* B1 = (float*)(ws + 393216);                     // 262144 B
    float* h1 = (float*)(ws + 655360);                     // 524288 B
    float* A2 = (float*)(ws + 1179648);                    // 262144 B
    float* B2 = (float*)(ws + 1441792);                    // 262144 B
    float* h2 = (float*)(ws + 1703936);                    // 2097152 B
    unsigned short* Wpk1 = (unsigned short*)(ws + 3801088); // 16384 B
    unsigned short* Wpk2 = (unsigned short*)(ws + 3817472); // 65536 B
    float* partial = (float*)(ws + 3883008);               // 4194304 B (KSPLIT=4 x 1MB)
    // total 8077312 B

    k_zero_adj<<<dim3((N_NODES * ADJ_WORDS + 255) / 256), dim3(256), 0, stream>>>(adj);
    k_build_adj<<<dim3(N_EDGES / 256), dim3(256), 0, stream>>>(ei, adj);
    k_pack_w<<<dim3(4), dim3(256), 0, stream>>>(W2, Wpk1, HID_C);
    k_pack_w<<<dim3(16), dim3(256), 0, stream>>>(W4, Wpk2, OUT_C);
    k_xform1<<<dim3(N_NODES), dim3(64), 0, stream>>>(x, W1, b1, A1, B1);
    k_conv_mfma<2, HID_C><<<dim3(N_NODES), dim3(256), 0, stream>>>(adj, A1, B1, Wpk1, b2, h1);
    k_xform2<<<dim3(N_NODES), dim3(64), 0, stream>>>(h1, W3, b3, A2, B2);
    k_conv_mfma<8, OUT_C><<<dim3(N_NODES), dim3(256), 0, stream>>>(adj, A2, B2, Wpk2, b4, h2);
    k_readout_part<<<dim3(64 * KSPLIT), dim3(256), 0, stream>>>(h2, Wr, partial);
    k_readout_reduce<<<dim3(256), dim3(256), 0, stream>>>(partial, br, out);
}